// Round 1
// baseline (1141.847 us; speedup 1.0000x reference)
//
#include <hip/hip_runtime.h>
#include <math.h>

#define Hdim 4096
#define Vdim 32000
#define MTOK 2048
#define BM 128
#define BV 128
#define BK 64
#define NSTRIPS (Vdim / BV)   /* 250 */
#define NMT (MTOK / BM)       /* 16 */

#define IGNORE_INDEX (-100)
#define BETA 0.1f
#define ALPHA 1.0f
#define SIMPO_GAMMA 0.5f
#define LABEL_SMOOTHING 0.0f

typedef __attribute__((ext_vector_type(8))) short bf16x8;
typedef __attribute__((ext_vector_type(4))) float f32x4;

static __device__ __forceinline__ short f2bf(float f) {
    unsigned int u = __float_as_uint(f);
    u = u + 0x7fffu + ((u >> 16) & 1u);   // RNE
    return (short)(u >> 16);
}

static __device__ __forceinline__ f32x4 vmax4(f32x4 a, f32x4 b) {
    f32x4 r;
    r[0] = fmaxf(a[0], b[0]); r[1] = fmaxf(a[1], b[1]);
    r[2] = fmaxf(a[2], b[2]); r[3] = fmaxf(a[3], b[3]);
    return r;
}

// ---------------------------------------------------------------------------
// Kernel 1: logits tile GEMM (bf16 MFMA) + per-strip online-softmax partials
// grid: NSTRIPS * NMT blocks of 256 threads. block b: mt = b & 15, vt = b >> 4
// ---------------------------------------------------------------------------
__global__ __launch_bounds__(256, 2)
void k_gemm_lse(const float* __restrict__ x, const float* __restrict__ W,
                const int* __restrict__ y,
                float* __restrict__ pmax, float* __restrict__ psum,
                float* __restrict__ tgt)
{
    const int bid = blockIdx.x;
    const int mt = bid & (NMT - 1);
    const int vt = bid >> 4;          // NMT == 16
    const int m0 = mt * BM;
    const int v0 = vt * BV;
    const int tid = threadIdx.x;
    const int lane = tid & 63;
    const int wid = tid >> 6;
    const int wm = (wid >> 1) * 64;   // wave row offset in tile
    const int wv = (wid & 1) * 64;    // wave col offset in tile

    __shared__ short lsA[BM * BK];    // 16 KB, row stride 64 shorts, XOR-swizzled
    __shared__ short lsB[BV * BK];    // 16 KB
    __shared__ int   yloc[BM];
    __shared__ float wredM[4][64];
    __shared__ float wredS[4][64];

    if (tid < BM) yloc[tid] = y[m0 + tid];

    f32x4 acc[4][4];
#pragma unroll
    for (int i = 0; i < 4; i++)
#pragma unroll
        for (int j = 0; j < 4; j++) acc[i][j] = (f32x4)(0.0f);

    const int srow = tid >> 3;        // 0..31
    const int skb  = tid & 7;         // 0..7
    const float* xg = x + (size_t)m0 * Hdim;
    const float* wg = W + (size_t)v0 * Hdim;

#pragma unroll 1
    for (int kt = 0; kt < Hdim / BK; ++kt) {
        const int k0 = kt * BK;
        __syncthreads();
        // ---- stage A (x) and B (W) tiles: f32 -> bf16, swizzled ds_write_b128
#pragma unroll
        for (int t = 0; t < 4; t++) {
            const int row  = t * 32 + srow;
            const int slot = skb ^ (row & 7);
            const float* pa = xg + (size_t)row * Hdim + k0 + skb * 8;
            const float* pb = wg + (size_t)row * Hdim + k0 + skb * 8;
            float4 a0 = *(const float4*)(pa);
            float4 a1 = *(const float4*)(pa + 4);
            float4 b0 = *(const float4*)(pb);
            float4 b1 = *(const float4*)(pb + 4);
            bf16x8 va, vb;
            va[0] = f2bf(a0.x); va[1] = f2bf(a0.y); va[2] = f2bf(a0.z); va[3] = f2bf(a0.w);
            va[4] = f2bf(a1.x); va[5] = f2bf(a1.y); va[6] = f2bf(a1.z); va[7] = f2bf(a1.w);
            vb[0] = f2bf(b0.x); vb[1] = f2bf(b0.y); vb[2] = f2bf(b0.z); vb[3] = f2bf(b0.w);
            vb[4] = f2bf(b1.x); vb[5] = f2bf(b1.y); vb[6] = f2bf(b1.z); vb[7] = f2bf(b1.w);
            *reinterpret_cast<bf16x8*>(&lsA[row * 64 + slot * 8]) = va;
            *reinterpret_cast<bf16x8*>(&lsB[row * 64 + slot * 8]) = vb;
        }
        __syncthreads();
        // ---- MFMA: 2 k-substeps of 32
#pragma unroll
        for (int ks = 0; ks < 2; ++ks) {
            bf16x8 af[4], bfr[4];
            const int kb = ks * 4 + (lane >> 4);
#pragma unroll
            for (int i = 0; i < 4; i++) {
                const int row = wm + i * 16 + (lane & 15);
                af[i] = *reinterpret_cast<const bf16x8*>(&lsA[row * 64 + (kb ^ (row & 7)) * 8]);
            }
#pragma unroll
            for (int j = 0; j < 4; j++) {
                const int row = wv + j * 16 + (lane & 15);
                bfr[j] = *reinterpret_cast<const bf16x8*>(&lsB[row * 64 + (kb ^ (row & 7)) * 8]);
            }
#pragma unroll
            for (int i = 0; i < 4; i++)
#pragma unroll
                for (int j = 0; j < 4; j++)
                    acc[i][j] = __builtin_amdgcn_mfma_f32_16x16x32_bf16(af[i], bfr[j], acc[i][j], 0, 0, 0);
        }
    }

    __syncthreads();

    // ---- target-logit extraction
    // C layout (m89): col = lane&15, row = (lane>>4)*4 + reg
    {
        const int colbase = v0 + wv + (lane & 15);
        const int rbase = wm + ((lane >> 4) << 2);
#pragma unroll
        for (int i = 0; i < 4; i++) {
#pragma unroll
            for (int r = 0; r < 4; r++) {
                const int rloc = rbase + i * 16 + r;
                const int yv = yloc[rloc];
#pragma unroll
                for (int j = 0; j < 4; j++) {
                    if (yv == colbase + j * 16) tgt[m0 + rloc] = acc[i][j][r];
                }
            }
        }
    }

    // ---- per-row max over this wave's 64 cols
    f32x4 rm[4], rs[4];
#pragma unroll
    for (int i = 0; i < 4; i++) {
        rm[i] = acc[i][0];
#pragma unroll
        for (int j = 1; j < 4; j++) rm[i] = vmax4(rm[i], acc[i][j]);
#pragma unroll
        for (int off = 1; off < 16; off <<= 1) {
            f32x4 o;
#pragma unroll
            for (int r = 0; r < 4; r++) o[r] = __shfl_xor(rm[i][r], off);
            rm[i] = vmax4(rm[i], o);
        }
    }
    // ---- per-row sum of exp(logit - max)
#pragma unroll
    for (int i = 0; i < 4; i++) {
        f32x4 s = (f32x4)(0.0f);
#pragma unroll
        for (int j = 0; j < 4; j++)
#pragma unroll
            for (int r = 0; r < 4; r++) s[r] += expf(acc[i][j][r] - rm[i][r]);
#pragma unroll
        for (int off = 1; off < 16; off <<= 1) {
#pragma unroll
            for (int r = 0; r < 4; r++) s[r] += __shfl_xor(s[r], off);
        }
        rs[i] = s;
    }
    // ---- cross-wave (same rows, different col-halves) merge via LDS
    if ((lane & 15) == 0) {
        const int g = lane >> 4;
#pragma unroll
        for (int i = 0; i < 4; i++)
#pragma unroll
            for (int r = 0; r < 4; r++) {
                wredM[wid][i * 16 + g * 4 + r] = rm[i][r];
                wredS[wid][i * 16 + g * 4 + r] = rs[i][r];
            }
    }
    __syncthreads();
    if (tid < BM) {
        const int r = tid;
        const int g = r >> 6;         // 0: waves 0,1  1: waves 2,3
        const int rl = r & 63;
        const float ma = wredM[2 * g][rl],  mb = wredM[2 * g + 1][rl];
        const float sa = wredS[2 * g][rl],  sb = wredS[2 * g + 1][rl];
        const float M = fmaxf(ma, mb);
        const float S = sa * expf(ma - M) + sb * expf(mb - M);
        pmax[(size_t)vt * MTOK + m0 + r] = M;
        psum[(size_t)vt * MTOK + m0 + r] = S;
    }
}

// ---------------------------------------------------------------------------
// Kernel 2a: merge strip partials -> per-token logp
// ---------------------------------------------------------------------------
__global__ void k_finalize(const float* __restrict__ pmax, const float* __restrict__ psum,
                           const float* __restrict__ tgt, float* __restrict__ logp)
{
    const int m = blockIdx.x * blockDim.x + threadIdx.x;
    if (m >= MTOK) return;
    float M = -INFINITY;
    for (int s = 0; s < NSTRIPS; s++) M = fmaxf(M, pmax[(size_t)s * MTOK + m]);
    float S = 0.0f;
    for (int s = 0; s < NSTRIPS; s++)
        S += psum[(size_t)s * MTOK + m] * expf(pmax[(size_t)s * MTOK + m] - M);
    logp[m] = tgt[m] - (M + logf(S));
}

// ---------------------------------------------------------------------------
// Kernel 2b: per-sequence masked averages + SimPO loss (single block)
// ---------------------------------------------------------------------------
static __device__ __forceinline__ float logsig(float z) {
    return (z >= 0.0f) ? -log1pf(expf(-z)) : (z - log1pf(expf(z)));
}

__global__ void k_loss(const float* __restrict__ logp, const int* __restrict__ y,
                       float* __restrict__ out)
{
    const int tid = threadIdx.x;  // 256 threads
    __shared__ float sbv[4], sbc[4];
    __shared__ float seqsum[8], seqcnt[8];

    for (int s = 0; s < 8; s++) {
        const int m = s * 256 + tid;
        const int msk = (y[m] != IGNORE_INDEX) ? 1 : 0;
        float vv = msk ? logp[m] : 0.0f;
        float cc = (float)msk;
#pragma unroll
        for (int o = 32; o > 0; o >>= 1) {
            vv += __shfl_down(vv, o);
            cc += __shfl_down(cc, o);
        }
        if ((tid & 63) == 0) { sbv[tid >> 6] = vv; sbc[tid >> 6] = cc; }
        __syncthreads();
        if (tid == 0) {
            float a = 0, b = 0;
            for (int w = 0; w < 4; w++) { a += sbv[w]; b += sbc[w]; }
            seqsum[s] = a; seqcnt[s] = b;
        }
        __syncthreads();
    }
    if (tid == 0) {
        float avg[8];
        for (int s = 0; s < 8; s++) avg[s] = seqsum[s] / seqcnt[s];
        float nsum = 0, ncnt = 0;
        for (int s = 0; s < 4; s++) { nsum += seqsum[s]; ncnt += seqcnt[s]; }
        const float nll = -nsum / ncnt;
        float lsum = 0;
        for (int i = 0; i < 4; i++) {
            const float d = avg[i] - avg[i + 4] - SIMPO_GAMMA / BETA;
            const float z = BETA * d;
            lsum += logsig(z) * (1.0f - LABEL_SMOOTHING) + logsig(-z) * LABEL_SMOOTHING;
        }
        out[0] = nll * ALPHA - lsum * 0.25f;
    }
}

// ---------------------------------------------------------------------------
extern "C" void kernel_launch(void* const* d_in, const int* in_sizes, int n_in,
                              void* d_out, int out_size, void* d_ws, size_t ws_size,
                              hipStream_t stream)
{
    const float* x = (const float*)d_in[0];
    const float* W = (const float*)d_in[1];
    const int*   y = (const int*)d_in[2];
    float* out = (float*)d_out;

    float* pmax = (float*)d_ws;                       // NSTRIPS*MTOK
    float* psum = pmax + (size_t)NSTRIPS * MTOK;      // NSTRIPS*MTOK
    float* tgt  = psum + (size_t)NSTRIPS * MTOK;      // MTOK
    float* logp = tgt + MTOK;                         // MTOK

    k_gemm_lse<<<dim3(NSTRIPS * NMT), dim3(256), 0, stream>>>(x, W, y, pmax, psum, tgt);
    k_finalize<<<dim3(MTOK / 256), dim3(256), 0, stream>>>(pmax, psum, tgt, logp);
    k_loss<<<dim3(1), dim3(256), 0, stream>>>(logp, y, out);
}

// Round 2
// 879.482 us; speedup vs baseline: 1.2983x; 1.2983x over previous
//
#include <hip/hip_runtime.h>
#include <math.h>

#define Hdim 4096
#define Vdim 32000
#define MTOK 2048
#define BM 128
#define BV 128
#define BK 64
#define NSTRIPS (Vdim / BV)   /* 250 */
#define NMT (MTOK / BM)       /* 16 */

#define IGNORE_INDEX (-100)
#define BETA 0.1f
#define ALPHA 1.0f
#define SIMPO_GAMMA 0.5f
#define LABEL_SMOOTHING 0.0f

#define TILE_BYTES 16384                    /* 128 rows x 64 bf16 */
#define WT_BYTES (250ull * 64 * TILE_BYTES) /* 262,144,000 */
#define XT_BYTES (16ull * 64 * TILE_BYTES)  /*  16,777,216 */

typedef __attribute__((ext_vector_type(8))) short bf16x8;
typedef __attribute__((ext_vector_type(4))) float f32x4;

static __device__ __forceinline__ short f2bf(float f) {
    unsigned int u = __float_as_uint(f);
    u = u + 0x7fffu + ((u >> 16) & 1u);   // RNE
    return (short)(u >> 16);
}

static __device__ __forceinline__ f32x4 vmax4(f32x4 a, f32x4 b) {
    f32x4 r;
    r[0] = fmaxf(a[0], b[0]); r[1] = fmaxf(a[1], b[1]);
    r[2] = fmaxf(a[2], b[2]); r[3] = fmaxf(a[3], b[3]);
    return r;
}

static __device__ __forceinline__ void gload_lds16(const void* g, void* l) {
    __builtin_amdgcn_global_load_lds(
        (const __attribute__((address_space(1))) unsigned int*)g,
        (__attribute__((address_space(3))) unsigned int*)l,
        16, 0, 0);
}

// ---------------------------------------------------------------------------
// Conversion: f32 source -> bf16 tiles in ws, tile-contiguous, XOR-swizzled
// so a linear global_load_lds reproduces the swizzled LDS layout.
// chunk gc: tile = gc>>10 (= strip*64 + kt), cidx = gc&1023, row=cidx>>3, cb=cidx&7
// ---------------------------------------------------------------------------
__global__ void k_convW(const float* __restrict__ W, char* __restrict__ Wt)
{
    const unsigned int gc = blockIdx.x * 256 + threadIdx.x;   // < 16,384,000
    const unsigned int tile = gc >> 10;
    const unsigned int cidx = gc & 1023u;
    const unsigned int row = cidx >> 3, cb = cidx & 7u;
    const unsigned int v = (tile >> 6) * 128 + row;
    const unsigned int h = (tile & 63u) * 64 + cb * 8;
    const float* src = W + (size_t)v * Hdim + h;
    float4 a0 = *(const float4*)(src);
    float4 a1 = *(const float4*)(src + 4);
    bf16x8 o;
    o[0] = f2bf(a0.x); o[1] = f2bf(a0.y); o[2] = f2bf(a0.z); o[3] = f2bf(a0.w);
    o[4] = f2bf(a1.x); o[5] = f2bf(a1.y); o[6] = f2bf(a1.z); o[7] = f2bf(a1.w);
    *reinterpret_cast<bf16x8*>(Wt + (size_t)tile * TILE_BYTES + ((row << 3) + (cb ^ (row & 7u))) * 16) = o;
}

__global__ void k_convX(const float* __restrict__ x, char* __restrict__ Xt)
{
    const unsigned int gc = blockIdx.x * 256 + threadIdx.x;   // < 1,048,576
    const unsigned int tile = gc >> 10;
    const unsigned int cidx = gc & 1023u;
    const unsigned int row = cidx >> 3, cb = cidx & 7u;
    const unsigned int m = (tile >> 6) * 128 + row;
    const unsigned int h = (tile & 63u) * 64 + cb * 8;
    const float* src = x + (size_t)m * Hdim + h;
    float4 a0 = *(const float4*)(src);
    float4 a1 = *(const float4*)(src + 4);
    bf16x8 o;
    o[0] = f2bf(a0.x); o[1] = f2bf(a0.y); o[2] = f2bf(a0.z); o[3] = f2bf(a0.w);
    o[4] = f2bf(a1.x); o[5] = f2bf(a1.y); o[6] = f2bf(a1.z); o[7] = f2bf(a1.w);
    *reinterpret_cast<bf16x8*>(Xt + (size_t)tile * TILE_BYTES + ((row << 3) + (cb ^ (row & 7u))) * 16) = o;
}

// ---------------------------------------------------------------------------
// Fast GEMM: bf16 tiles from ws, global_load_lds staging, 2-phase LDS dbuf
// ---------------------------------------------------------------------------
__global__ __launch_bounds__(256, 2)
void k_gemm_lse2(const char* __restrict__ Wt, const char* __restrict__ Xt,
                 const int* __restrict__ y,
                 float* __restrict__ pmax, float* __restrict__ psum,
                 float* __restrict__ tgt)
{
    const int bid = blockIdx.x;
    const int mt = bid & (NMT - 1);
    const int vt = bid >> 4;
    const int m0 = mt * BM;
    const int v0 = vt * BV;
    const int tid = threadIdx.x;
    const int lane = tid & 63;
    const int wid = tid >> 6;
    const int wm = (wid >> 1) * 64;
    const int wv = (wid & 1) * 64;

    __shared__ char lds[2][2 * TILE_BYTES];   // [buf][A 16KB | B 16KB]
    __shared__ int   yloc[BM];
    __shared__ float wredM[4][64];
    __shared__ float wredS[4][64];

    if (tid < BM) yloc[tid] = y[m0 + tid];

    f32x4 acc[4][4];
#pragma unroll
    for (int i = 0; i < 4; i++)
#pragma unroll
        for (int j = 0; j < 4; j++) acc[i][j] = (f32x4)(0.0f);

    const char* gA = Xt + (size_t)mt * 64 * TILE_BYTES;   // + kt*TILE_BYTES
    const char* gB = Wt + (size_t)vt * 64 * TILE_BYTES;

    // ---- prologue: stage kt=0 into buf 0
    {
        char* lA = &lds[0][0];
        char* lB = &lds[0][TILE_BYTES];
#pragma unroll
        for (int i = 0; i < 4; i++) {
            const int off = wid * 4096 + i * 1024;
            gload_lds16(gA + off + lane * 16, lA + off);
            gload_lds16(gB + off + lane * 16, lB + off);
        }
    }
    __syncthreads();

#pragma unroll 1
    for (int kt = 0; kt < Hdim / BK; ++kt) {
        const int cur = kt & 1;
        // ---- stage next tile into the other buffer (overlaps compute)
        if (kt < Hdim / BK - 1) {
            const char* gAn = gA + (size_t)(kt + 1) * TILE_BYTES;
            const char* gBn = gB + (size_t)(kt + 1) * TILE_BYTES;
            char* lA = &lds[cur ^ 1][0];
            char* lB = &lds[cur ^ 1][TILE_BYTES];
#pragma unroll
            for (int i = 0; i < 4; i++) {
                const int off = wid * 4096 + i * 1024;
                gload_lds16(gAn + off + lane * 16, lA + off);
                gload_lds16(gBn + off + lane * 16, lB + off);
            }
        }
        // ---- compute from current buffer
        const short* lsA = (const short*)&lds[cur][0];
        const short* lsB = (const short*)&lds[cur][TILE_BYTES];
#pragma unroll
        for (int ks = 0; ks < 2; ++ks) {
            bf16x8 af[4], bfr[4];
            const int kb = ks * 4 + (lane >> 4);
#pragma unroll
            for (int i = 0; i < 4; i++) {
                const int row = wm + i * 16 + (lane & 15);
                af[i] = *reinterpret_cast<const bf16x8*>(&lsA[row * 64 + (kb ^ (row & 7)) * 8]);
            }
#pragma unroll
            for (int j = 0; j < 4; j++) {
                const int row = wv + j * 16 + (lane & 15);
                bfr[j] = *reinterpret_cast<const bf16x8*>(&lsB[row * 64 + (kb ^ (row & 7)) * 8]);
            }
#pragma unroll
            for (int i = 0; i < 4; i++)
#pragma unroll
                for (int j = 0; j < 4; j++)
                    acc[i][j] = __builtin_amdgcn_mfma_f32_16x16x32_bf16(af[i], bfr[j], acc[i][j], 0, 0, 0);
        }
        __syncthreads();   // drains vmcnt(0): next buffer staged; lds reads done
    }

    // ---- target-logit extraction (C layout m89: col=lane&15, row=(lane>>4)*4+r)
    {
        const int colbase = v0 + wv + (lane & 15);
        const int rbase = wm + ((lane >> 4) << 2);
#pragma unroll
        for (int i = 0; i < 4; i++) {
#pragma unroll
            for (int r = 0; r < 4; r++) {
                const int rloc = rbase + i * 16 + r;
                const int yv = yloc[rloc];
#pragma unroll
                for (int j = 0; j < 4; j++) {
                    if (yv == colbase + j * 16) tgt[m0 + rloc] = acc[i][j][r];
                }
            }
        }
    }

    // ---- per-row max over this wave's 64 cols
    f32x4 rm[4], rs[4];
#pragma unroll
    for (int i = 0; i < 4; i++) {
        rm[i] = acc[i][0];
#pragma unroll
        for (int j = 1; j < 4; j++) rm[i] = vmax4(rm[i], acc[i][j]);
#pragma unroll
        for (int off = 1; off < 16; off <<= 1) {
            f32x4 o;
#pragma unroll
            for (int r = 0; r < 4; r++) o[r] = __shfl_xor(rm[i][r], off);
            rm[i] = vmax4(rm[i], o);
        }
    }
#pragma unroll
    for (int i = 0; i < 4; i++) {
        f32x4 s = (f32x4)(0.0f);
#pragma unroll
        for (int j = 0; j < 4; j++)
#pragma unroll
            for (int r = 0; r < 4; r++) s[r] += expf(acc[i][j][r] - rm[i][r]);
#pragma unroll
        for (int off = 1; off < 16; off <<= 1) {
#pragma unroll
            for (int r = 0; r < 4; r++) s[r] += __shfl_xor(s[r], off);
        }
        rs[i] = s;
    }
    if ((lane & 15) == 0) {
        const int g = lane >> 4;
#pragma unroll
        for (int i = 0; i < 4; i++)
#pragma unroll
            for (int r = 0; r < 4; r++) {
                wredM[wid][i * 16 + g * 4 + r] = rm[i][r];
                wredS[wid][i * 16 + g * 4 + r] = rs[i][r];
            }
    }
    __syncthreads();
    if (tid < BM) {
        const int r = tid;
        const int g = r >> 6;
        const int rl = r & 63;
        const float ma = wredM[2 * g][rl],  mb = wredM[2 * g + 1][rl];
        const float sa = wredS[2 * g][rl],  sb = wredS[2 * g + 1][rl];
        const float M = fmaxf(ma, mb);
        const float S = sa * expf(ma - M) + sb * expf(mb - M);
        pmax[(size_t)vt * MTOK + m0 + r] = M;
        psum[(size_t)vt * MTOK + m0 + r] = S;
    }
}

// ---------------------------------------------------------------------------
// Fallback GEMM (round-1, in-loop conversion) for small ws_size
// ---------------------------------------------------------------------------
__global__ __launch_bounds__(256, 2)
void k_gemm_lse_fb(const float* __restrict__ x, const float* __restrict__ W,
                   const int* __restrict__ y,
                   float* __restrict__ pmax, float* __restrict__ psum,
                   float* __restrict__ tgt)
{
    const int bid = blockIdx.x;
    const int mt = bid & (NMT - 1);
    const int vt = bid >> 4;
    const int m0 = mt * BM;
    const int v0 = vt * BV;
    const int tid = threadIdx.x;
    const int lane = tid & 63;
    const int wid = tid >> 6;
    const int wm = (wid >> 1) * 64;
    const int wv = (wid & 1) * 64;

    __shared__ short lsA[BM * BK];
    __shared__ short lsB[BV * BK];
    __shared__ int   yloc[BM];
    __shared__ float wredM[4][64];
    __shared__ float wredS[4][64];

    if (tid < BM) yloc[tid] = y[m0 + tid];

    f32x4 acc[4][4];
#pragma unroll
    for (int i = 0; i < 4; i++)
#pragma unroll
        for (int j = 0; j < 4; j++) acc[i][j] = (f32x4)(0.0f);

    const int srow = tid >> 3;
    const int skb  = tid & 7;
    const float* xg = x + (size_t)m0 * Hdim;
    const float* wg = W + (size_t)v0 * Hdim;

#pragma unroll 1
    for (int kt = 0; kt < Hdim / BK; ++kt) {
        const int k0 = kt * BK;
        __syncthreads();
#pragma unroll
        for (int t = 0; t < 4; t++) {
            const int row  = t * 32 + srow;
            const int slot = skb ^ (row & 7);
            const float* pa = xg + (size_t)row * Hdim + k0 + skb * 8;
            const float* pb = wg + (size_t)row * Hdim + k0 + skb * 8;
            float4 a0 = *(const float4*)(pa);
            float4 a1 = *(const float4*)(pa + 4);
            float4 b0 = *(const float4*)(pb);
            float4 b1 = *(const float4*)(pb + 4);
            bf16x8 va, vb;
            va[0] = f2bf(a0.x); va[1] = f2bf(a0.y); va[2] = f2bf(a0.z); va[3] = f2bf(a0.w);
            va[4] = f2bf(a1.x); va[5] = f2bf(a1.y); va[6] = f2bf(a1.z); va[7] = f2bf(a1.w);
            vb[0] = f2bf(b0.x); vb[1] = f2bf(b0.y); vb[2] = f2bf(b0.z); vb[3] = f2bf(b0.w);
            vb[4] = f2bf(b1.x); vb[5] = f2bf(b1.y); vb[6] = f2bf(b1.z); vb[7] = f2bf(b1.w);
            *reinterpret_cast<bf16x8*>(&lsA[row * 64 + slot * 8]) = va;
            *reinterpret_cast<bf16x8*>(&lsB[row * 64 + slot * 8]) = vb;
        }
        __syncthreads();
#pragma unroll
        for (int ks = 0; ks < 2; ++ks) {
            bf16x8 af[4], bfr[4];
            const int kb = ks * 4 + (lane >> 4);
#pragma unroll
            for (int i = 0; i < 4; i++) {
                const int row = wm + i * 16 + (lane & 15);
                af[i] = *reinterpret_cast<const bf16x8*>(&lsA[row * 64 + (kb ^ (row & 7)) * 8]);
            }
#pragma unroll
            for (int j = 0; j < 4; j++) {
                const int row = wv + j * 16 + (lane & 15);
                bfr[j] = *reinterpret_cast<const bf16x8*>(&lsB[row * 64 + (kb ^ (row & 7)) * 8]);
            }
#pragma unroll
            for (int i = 0; i < 4; i++)
#pragma unroll
                for (int j = 0; j < 4; j++)
                    acc[i][j] = __builtin_amdgcn_mfma_f32_16x16x32_bf16(af[i], bfr[j], acc[i][j], 0, 0, 0);
        }
    }

    __syncthreads();
    {
        const int colbase = v0 + wv + (lane & 15);
        const int rbase = wm + ((lane >> 4) << 2);
#pragma unroll
        for (int i = 0; i < 4; i++) {
#pragma unroll
            for (int r = 0; r < 4; r++) {
                const int rloc = rbase + i * 16 + r;
                const int yv = yloc[rloc];
#pragma unroll
                for (int j = 0; j < 4; j++) {
                    if (yv == colbase + j * 16) tgt[m0 + rloc] = acc[i][j][r];
                }
            }
        }
    }
    f32x4 rm[4], rs[4];
#pragma unroll
    for (int i = 0; i < 4; i++) {
        rm[i] = acc[i][0];
#pragma unroll
        for (int j = 1; j < 4; j++) rm[i] = vmax4(rm[i], acc[i][j]);
#pragma unroll
        for (int off = 1; off < 16; off <<= 1) {
            f32x4 o;
#pragma unroll
            for (int r = 0; r < 4; r++) o[r] = __shfl_xor(rm[i][r], off);
            rm[i] = vmax4(rm[i], o);
        }
    }
#pragma unroll
    for (int i = 0; i < 4; i++) {
        f32x4 s = (f32x4)(0.0f);
#pragma unroll
        for (int j = 0; j < 4; j++)
#pragma unroll
            for (int r = 0; r < 4; r++) s[r] += expf(acc[i][j][r] - rm[i][r]);
#pragma unroll
        for (int off = 1; off < 16; off <<= 1) {
#pragma unroll
            for (int r = 0; r < 4; r++) s[r] += __shfl_xor(s[r], off);
        }
        rs[i] = s;
    }
    if ((lane & 15) == 0) {
        const int g = lane >> 4;
#pragma unroll
        for (int i = 0; i < 4; i++)
#pragma unroll
            for (int r = 0; r < 4; r++) {
                wredM[wid][i * 16 + g * 4 + r] = rm[i][r];
                wredS[wid][i * 16 + g * 4 + r] = rs[i][r];
            }
    }
    __syncthreads();
    if (tid < BM) {
        const int r = tid;
        const int g = r >> 6;
        const int rl = r & 63;
        const float ma = wredM[2 * g][rl],  mb = wredM[2 * g + 1][rl];
        const float sa = wredS[2 * g][rl],  sb = wredS[2 * g + 1][rl];
        const float M = fmaxf(ma, mb);
        const float S = sa * expf(ma - M) + sb * expf(mb - M);
        pmax[(size_t)vt * MTOK + m0 + r] = M;
        psum[(size_t)vt * MTOK + m0 + r] = S;
    }
}

// ---------------------------------------------------------------------------
__global__ void k_finalize(const float* __restrict__ pmax, const float* __restrict__ psum,
                           const float* __restrict__ tgt, float* __restrict__ logp)
{
    const int m = blockIdx.x * blockDim.x + threadIdx.x;
    if (m >= MTOK) return;
    float M = -INFINITY;
    for (int s = 0; s < NSTRIPS; s++) M = fmaxf(M, pmax[(size_t)s * MTOK + m]);
    float S = 0.0f;
    for (int s = 0; s < NSTRIPS; s++)
        S += psum[(size_t)s * MTOK + m] * expf(pmax[(size_t)s * MTOK + m] - M);
    logp[m] = tgt[m] - (M + logf(S));
}

static __device__ __forceinline__ float logsig(float z) {
    return (z >= 0.0f) ? -log1pf(expf(-z)) : (z - log1pf(expf(z)));
}

__global__ void k_loss(const float* __restrict__ logp, const int* __restrict__ y,
                       float* __restrict__ out)
{
    const int tid = threadIdx.x;
    __shared__ float sbv[4], sbc[4];
    __shared__ float seqsum[8], seqcnt[8];

    for (int s = 0; s < 8; s++) {
        const int m = s * 256 + tid;
        const int msk = (y[m] != IGNORE_INDEX) ? 1 : 0;
        float vv = msk ? logp[m] : 0.0f;
        float cc = (float)msk;
#pragma unroll
        for (int o = 32; o > 0; o >>= 1) {
            vv += __shfl_down(vv, o);
            cc += __shfl_down(cc, o);
        }
        if ((tid & 63) == 0) { sbv[tid >> 6] = vv; sbc[tid >> 6] = cc; }
        __syncthreads();
        if (tid == 0) {
            float a = 0, b = 0;
            for (int w = 0; w < 4; w++) { a += sbv[w]; b += sbc[w]; }
            seqsum[s] = a; seqcnt[s] = b;
        }
        __syncthreads();
    }
    if (tid == 0) {
        float avg[8];
        for (int s = 0; s < 8; s++) avg[s] = seqsum[s] / seqcnt[s];
        float nsum = 0, ncnt = 0;
        for (int s = 0; s < 4; s++) { nsum += seqsum[s]; ncnt += seqcnt[s]; }
        const float nll = -nsum / ncnt;
        float lsum = 0;
        for (int i = 0; i < 4; i++) {
            const float d = avg[i] - avg[i + 4] - SIMPO_GAMMA / BETA;
            const float z = BETA * d;
            lsum += logsig(z) * (1.0f - LABEL_SMOOTHING) + logsig(-z) * LABEL_SMOOTHING;
        }
        out[0] = nll * ALPHA - lsum * 0.25f;
    }
}

// ---------------------------------------------------------------------------
extern "C" void kernel_launch(void* const* d_in, const int* in_sizes, int n_in,
                              void* d_out, int out_size, void* d_ws, size_t ws_size,
                              hipStream_t stream)
{
    const float* x = (const float*)d_in[0];
    const float* W = (const float*)d_in[1];
    const int*   y = (const int*)d_in[2];
    float* out = (float*)d_out;

    const size_t partials = (size_t)2 * NSTRIPS * MTOK * sizeof(float) + 2 * MTOK * sizeof(float);
    const size_t need = WT_BYTES + XT_BYTES + partials;

    if (ws_size >= need) {
        char* Wt = (char*)d_ws;
        char* Xt = Wt + WT_BYTES;
        float* pmax = (float*)(Xt + XT_BYTES);
        float* psum = pmax + (size_t)NSTRIPS * MTOK;
        float* tgt  = psum + (size_t)NSTRIPS * MTOK;
        float* logp = tgt + MTOK;
        k_convW<<<dim3(64000), dim3(256), 0, stream>>>(W, Wt);
        k_convX<<<dim3(4096), dim3(256), 0, stream>>>(x, Xt);
        k_gemm_lse2<<<dim3(NSTRIPS * NMT), dim3(256), 0, stream>>>(Wt, Xt, y, pmax, psum, tgt);
        k_finalize<<<dim3(MTOK / 256), dim3(256), 0, stream>>>(pmax, psum, tgt, logp);
        k_loss<<<dim3(1), dim3(256), 0, stream>>>(logp, y, out);
    } else {
        float* pmax = (float*)d_ws;
        float* psum = pmax + (size_t)NSTRIPS * MTOK;
        float* tgt  = psum + (size_t)NSTRIPS * MTOK;
        float* logp = tgt + MTOK;
        k_gemm_lse_fb<<<dim3(NSTRIPS * NMT), dim3(256), 0, stream>>>(x, W, y, pmax, psum, tgt);
        k_finalize<<<dim3(MTOK / 256), dim3(256), 0, stream>>>(pmax, psum, tgt, logp);
        k_loss<<<dim3(1), dim3(256), 0, stream>>>(logp, y, out);
    }
}